// Round 25
// baseline (82.951 us; speedup 1.0000x reference)
//
#include <hip/hip_runtime.h>

#define HW   6144
#define WID  96
#define HEI  64
#define IC   243

// half-unit offsets in ws
#define HF1   0u
#define HL0   1572864u
#define HL1   3145728u
#define HL2   3538944u
#define WTH   3637248u
// float-unit offsets (half region ends at half idx 3670016 = float 1835008)
#define FYP   1835008u
#define FPART 3407872u
#define FST2  3432448u
// level-2 table, half units (float 3432480 * 2). size 2*6144*384 halfs -> ends 23.2MB
#define T2H   6864960u

typedef _Float16 v2h __attribute__((ext_vector_type(2)));
typedef _Float16 h8  __attribute__((ext_vector_type(8)));
typedef float f32x4 __attribute__((ext_vector_type(4)));

#if __has_builtin(__builtin_amdgcn_fdot2)
#define FDOT2(a,b,c) __builtin_amdgcn_fdot2((a),(b),(c),false)
#else
static __device__ __forceinline__ float fdot2_fb(v2h a, v2h b, float c){
    return c + (float)a[0]*(float)b[0] + (float)a[1]*(float)b[1];
}
#define FDOT2(a,b,c) fdot2_fb((a),(b),(c))
#endif

static __device__ __forceinline__ v2h g2(h8 v, int i){ v2h r; r[0]=v[2*i]; r[1]=v[2*i+1]; return r; }

// VALU-speed cross-lane add (DPP), correctness-proven R16/R18.
template<int CTRL>
static __device__ __forceinline__ float dppadd(float x) {
    int t = __builtin_amdgcn_update_dpp(0, __builtin_bit_cast(int, x), CTRL, 0xf, 0xf, false);
    return x + __builtin_bit_cast(float, t);
}

// LDS-tiled transpose [B,C,HW] f32 -> [pix][ch] fp16. grid (192, 4, 2)
__global__ void k_t(const float* __restrict__ f1, const float* __restrict__ f2,
                    float* __restrict__ ws) {
    _Float16* wh = (_Float16*)ws;
    const float* src = blockIdx.z ? f2 : f1;
    _Float16* dst = wh + (blockIdx.z ? HL0 : HF1);
    const int t = threadIdx.x;
    const int pix0 = blockIdx.x * 64;
    const int c0 = blockIdx.y * 32;
    const int b = pix0 / HW;
    const int pb = pix0 - b * HW;
    __shared__ float sT[32][65];
    const int px = t & 63;
    const int cb8 = (t >> 6) * 8;
    #pragma unroll
    for (int i = 0; i < 8; i++)
        sT[cb8 + i][px] = src[((size_t)(b * 128 + c0 + cb8 + i)) * HW + pb + px];
    __syncthreads();
    const int pw = t >> 2;
    const int cg = (t & 3) * 8;
    h8 hv;
    #pragma unroll
    for (int i = 0; i < 8; i++) hv[i] = (_Float16)sT[cg + i][pw];
    *(h8*)(dst + ((size_t)(pix0 + pw)) * 128 + c0 + cg) = hv;
}

// conv weights -> fp16 [o][k] padded to 256
__global__ void k_wt(const float* __restrict__ w, float* __restrict__ ws) {
    _Float16* wth = (_Float16*)ws + WTH;
    int tid = blockIdx.x * 256 + threadIdx.x;   // 0..32767
    int o = tid >> 8, k = tid & 255;
    wth[tid] = (k < IC) ? (_Float16)w[o * IC + k] : (_Float16)0.f;
}

// fp16 2x2 avg-pool, channel-last
__global__ void k_pool(const _Float16* __restrict__ src, _Float16* __restrict__ dst,
                       int Ho, int Wo) {
    int gt = blockIdx.x * 256 + threadIdx.x;
    int oc = gt & 15;
    int rest = gt >> 4;
    int x = rest % Wo; rest /= Wo;
    int y = rest % Ho; int b = rest / Ho;
    int Wi = Wo * 2;
    const _Float16* s = src + ((size_t)((b * (Ho * 2) + 2 * y) * Wi + 2 * x)) * 128 + oc * 8;
    h8 a  = *(const h8*)s;
    h8 bb = *(const h8*)(s + 128);
    h8 c  = *(const h8*)(s + (size_t)Wi * 128);
    h8 d  = *(const h8*)(s + (size_t)Wi * 128 + 128);
    h8 r;
    #pragma unroll
    for (int j = 0; j < 8; j++)
        r[j] = (_Float16)(0.25f * ((float)a[j] + (float)bb[j] + (float)c[j] + (float)d[j]));
    *(h8*)(dst + (size_t)gt * 8) = r;
}

// Level-2 full table via MFMA: T2[b][pix][cell] = scale * f1[pix].f2L2[cell].
// grid (384, 2), 256 thr. Pass loop NOT unrolled (R24 post-mortem: full unroll
// hoists 24 h8 loads -> ~120 VGPR live -> spill/serialize, the R17 signature).
__launch_bounds__(256)
__global__ void k_tab2(float* __restrict__ ws) {
    const _Float16* wh = (const _Float16*)ws;
    _Float16* t2 = (_Float16*)ws + T2H;
    const int b = blockIdx.y;
    const int pix0 = blockIdx.x * 16;          // local pixel base
    const int lane = threadIdx.x & 63;
    const int wv = __builtin_amdgcn_readfirstlane(threadIdx.x >> 6);
    const int p = lane & 15;
    const int kq = lane >> 4;
    __shared__ _Float16 sT2[16][388];          // pad 4 halfs
    const size_t pixg = (size_t)(b * HW + pix0 + p);
    const _Float16* f1p = wh + HF1 + pixg * 128 + kq * 8;
    const h8 bf0 = *(const h8*)(f1p);
    const h8 bf1 = *(const h8*)(f1p + 32);
    const h8 bf2 = *(const h8*)(f1p + 64);
    const h8 bf3 = *(const h8*)(f1p + 96);
    const _Float16* f2b = wh + HL2 + (size_t)b * 384 * 128;
    const float scale = 0.08838834764831845f;   // 1/sqrt(128)
    #pragma unroll 1
    for (int pass = 0; pass < 6; ++pass) {
        int cell0 = pass * 64 + wv * 16;
        const _Float16* ap = f2b + ((size_t)(cell0 + p)) * 128 + kq * 8;
        h8 a0 = *(const h8*)(ap);
        h8 a1 = *(const h8*)(ap + 32);
        h8 a2 = *(const h8*)(ap + 64);
        h8 a3 = *(const h8*)(ap + 96);
        f32x4 acc = {0.f, 0.f, 0.f, 0.f};
        acc = __builtin_amdgcn_mfma_f32_16x16x32_f16(a0, bf0, acc, 0, 0, 0);
        acc = __builtin_amdgcn_mfma_f32_16x16x32_f16(a1, bf1, acc, 0, 0, 0);
        acc = __builtin_amdgcn_mfma_f32_16x16x32_f16(a2, bf2, acc, 0, 0, 0);
        acc = __builtin_amdgcn_mfma_f32_16x16x32_f16(a3, bf3, acc, 0, 0, 0);
        // D row = cell (kq*4+reg), col = pixel p
        sT2[p][cell0 + kq * 4 + 0] = (_Float16)(acc[0] * scale);
        sT2[p][cell0 + kq * 4 + 1] = (_Float16)(acc[1] * scale);
        sT2[p][cell0 + kq * 4 + 2] = (_Float16)(acc[2] * scale);
        sT2[p][cell0 + kq * 4 + 3] = (_Float16)(acc[3] * scale);
    }
    __syncthreads();
    // bulk write: block region t2[(b*HW+pix0)*384 .. +16*384) is contiguous
    _Float16* dst = t2 + ((size_t)(b * HW + pix0)) * 384;
    const int t = threadIdx.x;
    #pragma unroll
    for (int i = 0; i < 3; ++i) {
        int idx = i * 256 + t;                 // 0..767, 8 halfs each
        int pr = idx / 48, c8 = idx - pr * 48;
        h8 v = *(const h8*)(&sT2[pr][c8 * 8]);
        *(h8*)(dst + (size_t)pr * 384 + c8 * 8) = v;
    }
}

// Fused: fdot2 taps (levels 0/1 direct; level 2 gathered from T2) + bilinear +
// MFMA 1x1 conv + GN partials. 256 thr, 8 px/block, grid 1536. XCD-pinned batches.
__launch_bounds__(256)
__global__ void k_corr_conv(const float* __restrict__ txy, const float* __restrict__ cb,
                            float* __restrict__ ws) {
    const _Float16* wh = (const _Float16*)ws;
    const int tid = threadIdx.x;
    const int j = blockIdx.x;           // 0..1535
    const int xcd = j & 7;
    const int slot = j >> 3;            // 0..191
    const int b = xcd >> 2;             // batch pinned to XCD half
    const int pblk = slot * 4 + (xcd & 3);   // 0..767 within batch
    const int pb0 = pblk * 8;
    const int pix0 = b * HW + pb0;

    __shared__ _Float16 sGh[8 * 300];    // [p][t]
    __shared__ _Float16 sFh[8 * 256];    // [p][k] XOR-swizzled in 16B units
    __shared__ float sLev[8 * 12];

    if (tid < 24) {
        int p = tid / 3, lev = tid - 3 * p;
        float tx = txy[(b * 2 + 0) * HW + pb0 + p];
        float ty = txy[(b * 2 + 1) * HW + pb0 + p];
        float inv = (lev == 0) ? 1.f : ((lev == 1) ? 0.5f : 0.25f);
        float xs = tx * inv, ys = ty * inv;
        float X0 = floorf(xs), Y0 = floorf(ys);
        sLev[p * 12 + lev * 4 + 0] = X0;
        sLev[p * 12 + lev * 4 + 1] = Y0;
        sLev[p * 12 + lev * 4 + 2] = xs - X0;
        sLev[p * 12 + lev * 4 + 3] = ys - Y0;
    }
    if (tid < 104) {   // zero sFh pad k in [243,256)
        int p = tid / 13, k = 243 + tid - (tid / 13) * 13;
        int kb = k >> 3, ke = k & 7;
        sFh[p * 256 + ((kb ^ (p & 7)) << 3) + ke] = (_Float16)0.f;
    }

    const int l = tid & 7;             // lane within 8-lane group
    const int grp8 = tid >> 3;         // 0..31
    const int p = grp8 >> 2;           // pixel 0..7
    const int rs = grp8 & 3;           // row-set: flat (lev,row) idx % 4
    const _Float16* f1p = wh + HF1 + ((size_t)(pix0 + p)) * 128 + l * 8;
    const h8 av0 = *(const h8*)(f1p);
    const h8 av1 = *(const h8*)(f1p + 64);

    __syncthreads();

    const float scale = 0.08838834764831845f;   // 1/sqrt(128)
    // levels 0 and 1 direct: flat = rs + it*4 covers 0..19 exactly
    for (int it = 0; it < 5; ++it) {
        int fl = rs + it * 4;                    // 0..19: lev = fl/10, row = fl%10
        int lev = (fl >= 10) ? 1 : 0;
        int row = fl - lev * 10;
        const int WL = WID >> lev, HL = HEI >> lev;
        const _Float16* f2b = wh + ((lev == 0) ? HL0 : HL1)
                              + (size_t)b * HL * WL * 128;
        const int X0 = (int)sLev[p * 12 + lev * 4 + 0];
        const int Y0 = (int)sLev[p * 12 + lev * 4 + 1];
        int y = Y0 - 4 + row;
        bool yok = (unsigned)y < (unsigned)HL;
        int yc = min(max(y, 0), HL - 1);
        const _Float16* rowp = f2b + (size_t)(yc * WL) * 128 + l * 8;
        _Float16* sGp = sGh + p * 300 + lev * 100 + row * 10;
        #pragma unroll
        for (int c4 = 0; c4 < 10; ++c4) {
            int x = X0 - 4 + c4;
            bool ok = yok && ((unsigned)x < (unsigned)WL);
            int xc = min(max(x, 0), WL - 1);
            const _Float16* colp = rowp + xc * 128;
            h8 bv0 = *(const h8*)(colp);
            h8 bv1 = *(const h8*)(colp + 64);
            float d = FDOT2(g2(av0, 0), g2(bv0, 0), 0.f);
            d = FDOT2(g2(av0, 1), g2(bv0, 1), d);
            d = FDOT2(g2(av0, 2), g2(bv0, 2), d);
            d = FDOT2(g2(av0, 3), g2(bv0, 3), d);
            d = FDOT2(g2(av1, 0), g2(bv1, 0), d);
            d = FDOT2(g2(av1, 1), g2(bv1, 1), d);
            d = FDOT2(g2(av1, 2), g2(bv1, 2), d);
            d = FDOT2(g2(av1, 3), g2(bv1, 3), d);
            d = dppadd<0xB1>(d);    // quad_perm [1,0,3,2]  (xor 1)
            d = dppadd<0x4E>(d);    // quad_perm [2,3,0,1]  (xor 2)
            d = dppadd<0x141>(d);   // row_half_mirror: partner quad sum
            if (l == 0) sGp[c4] = ok ? (_Float16)(d * scale) : (_Float16)0.f;
        }
    }
    // level 2 from precomputed table: 8 px * 100 taps = 800 2B gathers
    {
        const _Float16* t2 = wh + T2H;
        for (int idx = tid; idx < 800; idx += 256) {
            int pp = idx / 100;
            int rem = idx - pp * 100;
            int rr = rem / 10, cc = rem - rr * 10;
            int X0 = (int)sLev[pp * 12 + 2 * 4 + 0];
            int Y0 = (int)sLev[pp * 12 + 2 * 4 + 1];
            int y = Y0 - 4 + rr, x = X0 - 4 + cc;
            bool ok = ((unsigned)x < 24u) && ((unsigned)y < 16u);
            int xc = min(max(x, 0), 23), yc = min(max(y, 0), 15);
            _Float16 v = t2[((size_t)(pix0 + pp)) * 384 + yc * 24 + xc];
            sGh[pp * 300 + 200 + rr * 10 + cc] = ok ? v : (_Float16)0.f;
        }
    }
    __syncthreads();

    // bilinear combine -> sFh[p][k] fp16 (swizzled)
    for (int idx = tid; idx < 8 * IC; idx += 256) {
        int k = idx >> 3, p2 = idx & 7;
        int lev = (k < 81) ? 0 : ((k < 162) ? 1 : 2);
        int kk = k - lev * 81;
        int dyi = (kk * 57) >> 9, dxi = kk - 9 * dyi;
        float fx = sLev[p2 * 12 + lev * 4 + 2];
        float fy = sLev[p2 * 12 + lev * 4 + 3];
        const _Float16* Gp = sGh + p2 * 300 + lev * 100 + dyi * 10 + dxi;
        float v = (1.f - fy) * ((1.f - fx) * (float)Gp[0] + fx * (float)Gp[1])
                +        fy  * ((1.f - fx) * (float)Gp[10] + fx * (float)Gp[11]);
        int kb = k >> 3, ke = k & 7;
        sFh[p2 * 256 + ((kb ^ (p2 & 7)) << 3) + ke] = (_Float16)v;
    }
    __syncthreads();

    // 1x1 conv via MFMA: wave wv does out-tiles om = wv and wv+4 (B cols 8..15 unused)
    const int lane = tid & 63;
    const int wv = __builtin_amdgcn_readfirstlane(tid >> 6);
    const int pc = lane & 15;          // B column = pixel
    const int kq = lane >> 4;          // k-chunk
    const _Float16* wth = wh + WTH;
    const int om0 = wv, om1 = wv + 4;
    const _Float16* wtb0 = wth + (om0 * 16 + pc) * 256 + kq * 8;
    const _Float16* wtb1 = wth + (om1 * 16 + pc) * 256 + kq * 8;
    f32x4 acc0 = {0.f, 0.f, 0.f, 0.f}, acc1 = {0.f, 0.f, 0.f, 0.f};
    const int pcl = pc & 7;            // sFh has 8 pixels; cols 8..15 duplicate 0..7 (masked on write)
    #pragma unroll
    for (int s = 0; s < 8; ++s) {
        int kb = s * 4 + kq;
        h8 bvv = *(const h8*)(sFh + pcl * 256 + ((kb ^ (pcl & 7)) << 3));
        h8 a0 = *(const h8*)(wtb0 + s * 32);
        h8 a1 = *(const h8*)(wtb1 + s * 32);
        acc0 = __builtin_amdgcn_mfma_f32_16x16x32_f16(a0, bvv, acc0, 0, 0, 0);
        acc1 = __builtin_amdgcn_mfma_f32_16x16x32_f16(a1, bvv, acc1, 0, 0, 0);
    }
    const int row4 = kq * 4;
    float4 bb0 = *(const float4*)&cb[om0 * 16 + row4];
    float4 bb1 = *(const float4*)&cb[om1 * 16 + row4];
    float y00 = acc0[0] + bb0.x, y01 = acc0[1] + bb0.y, y02 = acc0[2] + bb0.z, y03 = acc0[3] + bb0.w;
    float y10 = acc1[0] + bb1.x, y11 = acc1[1] + bb1.y, y12 = acc1[2] + bb1.z, y13 = acc1[3] + bb1.w;
    if (pc < 8) {
        float* op0 = ws + FYP + ((size_t)(pix0 + pc)) * 128 + om0 * 16 + row4;
        float* op1 = ws + FYP + ((size_t)(pix0 + pc)) * 128 + om1 * 16 + row4;
        op0[0] = y00; op0[1] = y01; op0[2] = y02; op0[3] = y03;
        op1[0] = y10; op1[1] = y11; op1[2] = y12; op1[3] = y13;
    }
    // GN partial sums: wave-reduce, then plain per-block store (no atomics).
    // Indexed by LOGICAL block (b*768 + pblk) so k_gnred's per-batch sum holds.
    bool val = (pc < 8);
    float s0 = val ? (y00 + y01 + y02 + y03) : 0.f;
    float q0 = val ? (y00*y00 + y01*y01 + y02*y02 + y03*y03) : 0.f;
    float s1 = val ? (y10 + y11 + y12 + y13) : 0.f;
    float q1 = val ? (y10*y10 + y11*y11 + y12*y12 + y13*y13) : 0.f;
    #pragma unroll
    for (int m = 1; m < 64; m <<= 1) {
        s0 += __shfl_xor(s0, m);
        q0 += __shfl_xor(q0, m);
        s1 += __shfl_xor(s1, m);
        q1 += __shfl_xor(q1, m);
    }
    if (lane == 0) {
        float* pp = ws + FPART + (size_t)(b * 768 + pblk) * 16;
        pp[om0 * 2]     = s0;
        pp[om0 * 2 + 1] = q0;
        pp[om1 * 2]     = s1;
        pp[om1 * 2 + 1] = q1;
    }
}

// Reduce per-block GN partials: grid 16 (one per b*8+g), 256 thr
__global__ void k_gnred(float* __restrict__ ws) {
    const int bg = blockIdx.x;
    const int b = bg >> 3, om = bg & 7;
    const int t = threadIdx.x;
    float s = 0.f, q = 0.f;
    for (int blk = b * 768 + t; blk < (b + 1) * 768; blk += 256) {
        const float* pp = ws + FPART + (size_t)blk * 16 + om * 2;
        s += pp[0]; q += pp[1];
    }
    __shared__ float rs[256], rq[256];
    rs[t] = s; rq[t] = q;
    __syncthreads();
    for (int st = 128; st > 0; st >>= 1) {
        if (t < st) { rs[t] += rs[t + st]; rq[t] += rq[t + st]; }
        __syncthreads();
    }
    if (t == 0) {
        const float invN = 1.f / (float)(HW * 16);
        float mean = rs[0] * invN;
        float var = rq[0] * invN - mean * mean;
        ws[FST2 + bg * 2]     = mean;
        ws[FST2 + bg * 2 + 1] = rsqrtf(var + 1e-5f);
    }
}

// GN apply + LeakyReLU + transpose [pix][c] -> [b][c][pix]. grid 192, 256 thr
__global__ void k_finish(const float* __restrict__ gw, const float* __restrict__ gb,
                         const float* __restrict__ ws, float* __restrict__ out) {
    const int t = threadIdx.x;
    const int pix0 = blockIdx.x * 64;          // global pixel
    const int b = pix0 / HW;
    const int pb = pix0 - b * HW;
    __shared__ float sO[128][65];
    __shared__ float sM[8], sR[8];
    if (t < 8) {
        sM[t] = ws[FST2 + (b * 8 + t) * 2];
        sR[t] = ws[FST2 + (b * 8 + t) * 2 + 1];
    }
    __syncthreads();
    #pragma unroll
    for (int it = 0; it < 32; ++it) {
        int idx = it * 256 + t;                // 0..8191
        int px = idx >> 7, c = idx & 127;
        float v = ws[FYP + ((size_t)(pix0 + px)) * 128 + c];
        int g = c >> 4;
        v = (v - sM[g]) * sR[g] * gw[c] + gb[c];
        sO[c][px] = v > 0.f ? v : 0.1f * v;
    }
    __syncthreads();
    #pragma unroll
    for (int it = 0; it < 32; ++it) {
        int idx = it * 256 + t;
        int px = idx & 63, c = idx >> 6;
        out[((size_t)(b * 128 + c)) * HW + pb + px] = sO[c][px];
    }
}

extern "C" void kernel_launch(void* const* d_in, const int* in_sizes, int n_in,
                              void* d_out, int out_size, void* d_ws, size_t ws_size,
                              hipStream_t stream) {
    const float* f1  = (const float*)d_in[0];
    const float* f2  = (const float*)d_in[1];
    const float* txy = (const float*)d_in[2];
    const float* cw  = (const float*)d_in[3];
    const float* cb  = (const float*)d_in[4];
    const float* gw  = (const float*)d_in[5];
    const float* gb  = (const float*)d_in[6];
    float* ws = (float*)d_ws;
    _Float16* whp = (_Float16*)d_ws;
    float* out = (float*)d_out;

    k_t<<<dim3(192, 4, 2), 256, 0, stream>>>(f1, f2, ws);
    k_wt<<<128, 256, 0, stream>>>(cw, ws);
    k_pool<<<192, 256, 0, stream>>>(whp + HL0, whp + HL1, 32, 48);
    k_pool<<<48, 256, 0, stream>>>(whp + HL1, whp + HL2, 16, 24);
    k_tab2<<<dim3(384, 2), 256, 0, stream>>>(ws);
    k_corr_conv<<<1536, 256, 0, stream>>>(txy, cb, ws);
    k_gnred<<<16, 256, 0, stream>>>(ws);
    k_finish<<<192, 256, 0, stream>>>(gw, gb, ws, out);
}

// Round 26
// 75.278 us; speedup vs baseline: 1.1019x; 1.1019x over previous
//
#include <hip/hip_runtime.h>

#define HW   6144
#define WID  96
#define HEI  64
#define IC   243

// half-unit offsets in ws
#define HF1   0u
#define HL0   1572864u
#define HL1   3145728u
#define HL2   3538944u
#define WTH   3637248u
// float-unit offsets
#define FYP   1835008u
#define FPART 3407872u
#define FST2  3432448u

typedef _Float16 v2h __attribute__((ext_vector_type(2)));
typedef _Float16 h8  __attribute__((ext_vector_type(8)));
typedef float f32x4 __attribute__((ext_vector_type(4)));

#if __has_builtin(__builtin_amdgcn_fdot2)
#define FDOT2(a,b,c) __builtin_amdgcn_fdot2((a),(b),(c),false)
#else
static __device__ __forceinline__ float fdot2_fb(v2h a, v2h b, float c){
    return c + (float)a[0]*(float)b[0] + (float)a[1]*(float)b[1];
}
#define FDOT2(a,b,c) fdot2_fb((a),(b),(c))
#endif

static __device__ __forceinline__ v2h g2(h8 v, int i){ v2h r; r[0]=v[2*i]; r[1]=v[2*i+1]; return r; }

// VALU-speed cross-lane add (DPP), correctness-proven R16/R18.
template<int CTRL>
static __device__ __forceinline__ float dppadd(float x) {
    int t = __builtin_amdgcn_update_dpp(0, __builtin_bit_cast(int, x), CTRL, 0xf, 0xf, false);
    return x + __builtin_bit_cast(float, t);
}

// LDS-tiled transpose [B,C,HW] f32 -> [pix][ch] fp16. grid (192, 4, 2)
__global__ void k_t(const float* __restrict__ f1, const float* __restrict__ f2,
                    float* __restrict__ ws) {
    _Float16* wh = (_Float16*)ws;
    const float* src = blockIdx.z ? f2 : f1;
    _Float16* dst = wh + (blockIdx.z ? HL0 : HF1);
    const int t = threadIdx.x;
    const int pix0 = blockIdx.x * 64;
    const int c0 = blockIdx.y * 32;
    const int b = pix0 / HW;
    const int pb = pix0 - b * HW;
    __shared__ float sT[32][65];
    const int px = t & 63;
    const int cb8 = (t >> 6) * 8;
    #pragma unroll
    for (int i = 0; i < 8; i++)
        sT[cb8 + i][px] = src[((size_t)(b * 128 + c0 + cb8 + i)) * HW + pb + px];
    __syncthreads();
    const int pw = t >> 2;
    const int cg = (t & 3) * 8;
    h8 hv;
    #pragma unroll
    for (int i = 0; i < 8; i++) hv[i] = (_Float16)sT[cg + i][pw];
    *(h8*)(dst + ((size_t)(pix0 + pw)) * 128 + c0 + cg) = hv;
}

// Fused prep: blocks 0..383 = both pool levels (2 L2 cells/block, disjoint L1
// tiles, LDS handoff); blocks 384..511 = conv weight transform.
__global__ void k_prep(const float* __restrict__ w, float* __restrict__ ws) {
    _Float16* wh = (_Float16*)ws;
    const int blk = blockIdx.x;
    const int t = threadIdx.x;
    if (blk >= 384) {
        int idx = (blk - 384) * 256 + t;        // 0..32767
        int o = idx >> 8, k = idx & 255;
        wh[WTH + idx] = (k < IC) ? (_Float16)w[o * IC + k] : (_Float16)0.f;
        return;
    }
    __shared__ _Float16 sL1[8][128];
    // phase 1: 8 L1 cells (2 L2 cells x 4) x 16 chunks = 128 threads
    if (t < 128) {
        int li = t >> 4, oc = t & 15;
        int lc = li >> 2, sub = li & 3;
        int g2i = blk * 2 + lc;                  // global L2 cell
        int b = g2i / 384;
        int c2 = g2i - b * 384;
        int y2 = c2 / 24, x2 = c2 - y2 * 24;
        int y1 = y2 * 2 + (sub >> 1), x1 = x2 * 2 + (sub & 1);
        const _Float16* s = wh + HL0 + ((size_t)((b * 64 + 2 * y1) * 96 + 2 * x1)) * 128 + oc * 8;
        h8 a = *(const h8*)s;
        h8 bb = *(const h8*)(s + 128);
        h8 c = *(const h8*)(s + 96 * 128);
        h8 d = *(const h8*)(s + 96 * 128 + 128);
        h8 r;
        #pragma unroll
        for (int j = 0; j < 8; j++)
            r[j] = (_Float16)(0.25f * ((float)a[j] + (float)bb[j] + (float)c[j] + (float)d[j]));
        *(h8*)(wh + HL1 + ((size_t)((b * 32 + y1) * 48 + x1)) * 128 + oc * 8) = r;
        *(h8*)(&sL1[li][oc * 8]) = r;
    }
    __syncthreads();
    // phase 2: 2 L2 cells x 16 chunks = 32 threads
    if (t < 32) {
        int lc = t >> 4, oc = t & 15;
        int g2i = blk * 2 + lc;
        int b = g2i / 384;
        int c2 = g2i - b * 384;
        int y2 = c2 / 24, x2 = c2 - y2 * 24;
        h8 r;
        h8 a = *(const h8*)(&sL1[lc * 4 + 0][oc * 8]);
        h8 bb = *(const h8*)(&sL1[lc * 4 + 1][oc * 8]);
        h8 c = *(const h8*)(&sL1[lc * 4 + 2][oc * 8]);
        h8 d = *(const h8*)(&sL1[lc * 4 + 3][oc * 8]);
        #pragma unroll
        for (int j = 0; j < 8; j++)
            r[j] = (_Float16)(0.25f * ((float)a[j] + (float)bb[j] + (float)c[j] + (float)d[j]));
        *(h8*)(wh + HL2 + ((size_t)((b * 16 + y2) * 24 + x2)) * 128 + oc * 8) = r;
    }
}

// Fused: fdot2 taps (8-lane groups, split 4+4 chains, DPP reduce) + bilinear +
// MFMA 1x1 conv + GN partials. 256 thr, 8 px/block, grid 1536. XCD-pinned.
__launch_bounds__(256)
__global__ void k_corr_conv(const float* __restrict__ txy, const float* __restrict__ cb,
                            float* __restrict__ ws) {
    const _Float16* wh = (const _Float16*)ws;
    const int tid = threadIdx.x;
    const int j = blockIdx.x;           // 0..1535
    const int xcd = j & 7;
    const int slot = j >> 3;            // 0..191
    const int b = xcd >> 2;             // batch pinned to XCD half
    const int pblk = slot * 4 + (xcd & 3);   // 0..767 within batch
    const int pb0 = pblk * 8;
    const int pix0 = b * HW + pb0;

    __shared__ _Float16 sGh[8 * 300];    // [p][t]
    __shared__ _Float16 sFh[8 * 256];    // [p][k] XOR-swizzled in 16B units
    __shared__ float sLev[8 * 12];

    if (tid < 24) {
        int p = tid / 3, lev = tid - 3 * p;
        float tx = txy[(b * 2 + 0) * HW + pb0 + p];
        float ty = txy[(b * 2 + 1) * HW + pb0 + p];
        float inv = (lev == 0) ? 1.f : ((lev == 1) ? 0.5f : 0.25f);
        float xs = tx * inv, ys = ty * inv;
        float X0 = floorf(xs), Y0 = floorf(ys);
        sLev[p * 12 + lev * 4 + 0] = X0;
        sLev[p * 12 + lev * 4 + 1] = Y0;
        sLev[p * 12 + lev * 4 + 2] = xs - X0;
        sLev[p * 12 + lev * 4 + 3] = ys - Y0;
    }
    if (tid < 104) {   // zero sFh pad k in [243,256)
        int p = tid / 13, k = 243 + tid - (tid / 13) * 13;
        int kb = k >> 3, ke = k & 7;
        sFh[p * 256 + ((kb ^ (p & 7)) << 3) + ke] = (_Float16)0.f;
    }

    const int l = tid & 7;             // lane within 8-lane group
    const int grp8 = tid >> 3;         // 0..31
    const int p = grp8 >> 2;           // pixel 0..7
    const int rs = grp8 & 3;           // row-set: flat (lev,row) idx % 4
    const _Float16* f1p = wh + HF1 + ((size_t)(pix0 + p)) * 128 + l * 8;
    const h8 av0 = *(const h8*)(f1p);
    const h8 av1 = *(const h8*)(f1p + 64);

    __syncthreads();

    const float scale = 0.08838834764831845f;   // 1/sqrt(128)
    for (int it = 0; it < 8; ++it) {
        int flat = rs + it * 4;                  // 0..31: lev = flat/10, row = flat%10
        bool rowok = (flat < 30);
        int fl = rowok ? flat : 0;
        int lev = (fl >= 20) ? 2 : ((fl >= 10) ? 1 : 0);
        int row = fl - lev * 10;
        const int WL = WID >> lev, HL = HEI >> lev;
        const _Float16* f2b = wh + ((lev == 0) ? HL0 : ((lev == 1) ? HL1 : HL2))
                              + (size_t)b * HL * WL * 128;
        const int X0 = (int)sLev[p * 12 + lev * 4 + 0];
        const int Y0 = (int)sLev[p * 12 + lev * 4 + 1];
        int y = Y0 - 4 + row;
        bool yok = rowok && ((unsigned)y < (unsigned)HL);
        int yc = min(max(y, 0), HL - 1);
        const _Float16* rowp = f2b + (size_t)(yc * WL) * 128 + l * 8;
        _Float16* sGp = sGh + p * 300 + lev * 100 + row * 10;
        #pragma unroll
        for (int c4 = 0; c4 < 10; ++c4) {
            int x = X0 - 4 + c4;
            bool ok = yok && ((unsigned)x < (unsigned)WL);
            int xc = min(max(x, 0), WL - 1);
            const _Float16* colp = rowp + xc * 128;
            h8 bv0 = *(const h8*)(colp);
            h8 bv1 = *(const h8*)(colp + 64);
            float d0 = FDOT2(g2(av0, 0), g2(bv0, 0), 0.f);
            d0 = FDOT2(g2(av0, 1), g2(bv0, 1), d0);
            d0 = FDOT2(g2(av0, 2), g2(bv0, 2), d0);
            d0 = FDOT2(g2(av0, 3), g2(bv0, 3), d0);
            float d1 = FDOT2(g2(av1, 0), g2(bv1, 0), 0.f);
            d1 = FDOT2(g2(av1, 1), g2(bv1, 1), d1);
            d1 = FDOT2(g2(av1, 2), g2(bv1, 2), d1);
            d1 = FDOT2(g2(av1, 3), g2(bv1, 3), d1);
            float d = d0 + d1;
            d = dppadd<0xB1>(d);    // quad_perm [1,0,3,2]  (xor 1)
            d = dppadd<0x4E>(d);    // quad_perm [2,3,0,1]  (xor 2)
            d = dppadd<0x141>(d);   // row_half_mirror: partner quad sum
            if (l == 0 && rowok) sGp[c4] = ok ? (_Float16)(d * scale) : (_Float16)0.f;
        }
    }
    __syncthreads();

    // bilinear combine -> sFh[p][k] fp16 (swizzled)
    for (int idx = tid; idx < 8 * IC; idx += 256) {
        int k = idx >> 3, p2 = idx & 7;
        int lev = (k < 81) ? 0 : ((k < 162) ? 1 : 2);
        int kk = k - lev * 81;
        int dyi = (kk * 57) >> 9, dxi = kk - 9 * dyi;
        float fx = sLev[p2 * 12 + lev * 4 + 2];
        float fy = sLev[p2 * 12 + lev * 4 + 3];
        const _Float16* Gp = sGh + p2 * 300 + lev * 100 + dyi * 10 + dxi;
        float v = (1.f - fy) * ((1.f - fx) * (float)Gp[0] + fx * (float)Gp[1])
                +        fy  * ((1.f - fx) * (float)Gp[10] + fx * (float)Gp[11]);
        int kb = k >> 3, ke = k & 7;
        sFh[p2 * 256 + ((kb ^ (p2 & 7)) << 3) + ke] = (_Float16)v;
    }
    __syncthreads();

    // 1x1 conv via MFMA: wave wv does out-tiles om = wv and wv+4 (B cols 8..15 unused)
    const int lane = tid & 63;
    const int wv = __builtin_amdgcn_readfirstlane(tid >> 6);
    const int pc = lane & 15;          // B column = pixel
    const int kq = lane >> 4;          // k-chunk
    const _Float16* wth = wh + WTH;
    const int om0 = wv, om1 = wv + 4;
    const _Float16* wtb0 = wth + (om0 * 16 + pc) * 256 + kq * 8;
    const _Float16* wtb1 = wth + (om1 * 16 + pc) * 256 + kq * 8;
    f32x4 acc0 = {0.f, 0.f, 0.f, 0.f}, acc1 = {0.f, 0.f, 0.f, 0.f};
    const int pcl = pc & 7;            // sFh has 8 pixels; cols 8..15 duplicate 0..7 (masked on write)
    #pragma unroll
    for (int s = 0; s < 8; ++s) {
        int kb = s * 4 + kq;
        h8 bvv = *(const h8*)(sFh + pcl * 256 + ((kb ^ (pcl & 7)) << 3));
        h8 a0 = *(const h8*)(wtb0 + s * 32);
        h8 a1 = *(const h8*)(wtb1 + s * 32);
        acc0 = __builtin_amdgcn_mfma_f32_16x16x32_f16(a0, bvv, acc0, 0, 0, 0);
        acc1 = __builtin_amdgcn_mfma_f32_16x16x32_f16(a1, bvv, acc1, 0, 0, 0);
    }
    const int row4 = kq * 4;
    float4 bb0 = *(const float4*)&cb[om0 * 16 + row4];
    float4 bb1 = *(const float4*)&cb[om1 * 16 + row4];
    float y00 = acc0[0] + bb0.x, y01 = acc0[1] + bb0.y, y02 = acc0[2] + bb0.z, y03 = acc0[3] + bb0.w;
    float y10 = acc1[0] + bb1.x, y11 = acc1[1] + bb1.y, y12 = acc1[2] + bb1.z, y13 = acc1[3] + bb1.w;
    if (pc < 8) {
        float* op0 = ws + FYP + ((size_t)(pix0 + pc)) * 128 + om0 * 16 + row4;
        float* op1 = ws + FYP + ((size_t)(pix0 + pc)) * 128 + om1 * 16 + row4;
        op0[0] = y00; op0[1] = y01; op0[2] = y02; op0[3] = y03;
        op1[0] = y10; op1[1] = y11; op1[2] = y12; op1[3] = y13;
    }
    // GN partial sums: wave-reduce, then plain per-block store (no atomics).
    // Indexed by LOGICAL block (b*768 + pblk) so k_gnred's per-batch sum holds.
    bool val = (pc < 8);
    float s0 = val ? (y00 + y01 + y02 + y03) : 0.f;
    float q0 = val ? (y00*y00 + y01*y01 + y02*y02 + y03*y03) : 0.f;
    float s1 = val ? (y10 + y11 + y12 + y13) : 0.f;
    float q1 = val ? (y10*y10 + y11*y11 + y12*y12 + y13*y13) : 0.f;
    #pragma unroll
    for (int m = 1; m < 64; m <<= 1) {
        s0 += __shfl_xor(s0, m);
        q0 += __shfl_xor(q0, m);
        s1 += __shfl_xor(s1, m);
        q1 += __shfl_xor(q1, m);
    }
    if (lane == 0) {
        float* pp = ws + FPART + (size_t)(b * 768 + pblk) * 16;
        pp[om0 * 2]     = s0;
        pp[om0 * 2 + 1] = q0;
        pp[om1 * 2]     = s1;
        pp[om1 * 2 + 1] = q1;
    }
}

// Reduce per-block GN partials: grid 16 (one per b*8+g), 256 thr
__global__ void k_gnred(float* __restrict__ ws) {
    const int bg = blockIdx.x;
    const int b = bg >> 3, om = bg & 7;
    const int t = threadIdx.x;
    float s = 0.f, q = 0.f;
    for (int blk = b * 768 + t; blk < (b + 1) * 768; blk += 256) {
        const float* pp = ws + FPART + (size_t)blk * 16 + om * 2;
        s += pp[0]; q += pp[1];
    }
    __shared__ float rs[256], rq[256];
    rs[t] = s; rq[t] = q;
    __syncthreads();
    for (int st = 128; st > 0; st >>= 1) {
        if (t < st) { rs[t] += rs[t + st]; rq[t] += rq[t + st]; }
        __syncthreads();
    }
    if (t == 0) {
        const float invN = 1.f / (float)(HW * 16);
        float mean = rs[0] * invN;
        float var = rq[0] * invN - mean * mean;
        ws[FST2 + bg * 2]     = mean;
        ws[FST2 + bg * 2 + 1] = rsqrtf(var + 1e-5f);
    }
}

// GN apply + LeakyReLU + transpose [pix][c] -> [b][c][pix]. grid 192, 256 thr
__global__ void k_finish(const float* __restrict__ gw, const float* __restrict__ gb,
                         const float* __restrict__ ws, float* __restrict__ out) {
    const int t = threadIdx.x;
    const int pix0 = blockIdx.x * 64;          // global pixel
    const int b = pix0 / HW;
    const int pb = pix0 - b * HW;
    __shared__ float sO[128][65];
    __shared__ float sM[8], sR[8];
    if (t < 8) {
        sM[t] = ws[FST2 + (b * 8 + t) * 2];
        sR[t] = ws[FST2 + (b * 8 + t) * 2 + 1];
    }
    __syncthreads();
    #pragma unroll
    for (int it = 0; it < 32; ++it) {
        int idx = it * 256 + t;                // 0..8191
        int px = idx >> 7, c = idx & 127;
        float v = ws[FYP + ((size_t)(pix0 + px)) * 128 + c];
        int g = c >> 4;
        v = (v - sM[g]) * sR[g] * gw[c] + gb[c];
        sO[c][px] = v > 0.f ? v : 0.1f * v;
    }
    __syncthreads();
    #pragma unroll
    for (int it = 0; it < 32; ++it) {
        int idx = it * 256 + t;
        int px = idx & 63, c = idx >> 6;
        out[((size_t)(b * 128 + c)) * HW + pb + px] = sO[c][px];
    }
}

extern "C" void kernel_launch(void* const* d_in, const int* in_sizes, int n_in,
                              void* d_out, int out_size, void* d_ws, size_t ws_size,
                              hipStream_t stream) {
    const float* f1  = (const float*)d_in[0];
    const float* f2  = (const float*)d_in[1];
    const float* txy = (const float*)d_in[2];
    const float* cw  = (const float*)d_in[3];
    const float* cb  = (const float*)d_in[4];
    const float* gw  = (const float*)d_in[5];
    const float* gb  = (const float*)d_in[6];
    float* ws = (float*)d_ws;
    float* out = (float*)d_out;

    k_t<<<dim3(192, 4, 2), 256, 0, stream>>>(f1, f2, ws);
    k_prep<<<512, 256, 0, stream>>>(cw, ws);
    k_corr_conv<<<1536, 256, 0, stream>>>(txy, cb, ws);
    k_gnred<<<16, 256, 0, stream>>>(ws);
    k_finish<<<192, 256, 0, stream>>>(gw, gb, ws, out);
}